// Round 17
// baseline (105.923 us; speedup 1.0000x reference)
//
#include <hip/hip_runtime.h>
#include <math.h>

typedef unsigned short u16;
typedef unsigned int u32;
typedef float f32x4 __attribute__((ext_vector_type(4)));
typedef float f32x16 __attribute__((ext_vector_type(16)));
typedef u32 u32x4 __attribute__((ext_vector_type(4)));

// ---- problem dims: B=2 S=2048 E=1024 H=16 HD=64 ----
static const size_t TAB_B  = 0;         // float2[2048][32]
static const size_t QBF_B  = 524288;    // bf16 [2][16][2048][64], pre-scaled 0.125*log2e
static const size_t KBF_B  = 8912896;   // bf16 [2][16][2048][64]
static const size_t VTB_B  = 17301504;  // bf16 [2][16][64][2048]  (V transposed)
static const size_t W2H_B  = 25690112;  // fp16 [1024][1024]
static const size_t XBF_B  = 29884416;  // bf16 x      (dead after QKV gemm)
static const size_t W1BF_B = 38273024;  // bf16 w1     (dead after QKV gemm)
static const size_t O16_B  = 29884416;  // fp16 [4096][1024], reuses XBF

#if __has_builtin(__builtin_amdgcn_exp2f)
#define EXP2(x) __builtin_amdgcn_exp2f(x)
#else
#define EXP2(x) __expf(0.69314718056f * (x))
#endif

__device__ __forceinline__ u16 f2bf(float f) {
  u32 u = __builtin_bit_cast(u32, f);
  u += 0x7fffu + ((u >> 16) & 1u);
  return (u16)(u >> 16);
}
__device__ __forceinline__ float bf2f(u16 h) {
  return __builtin_bit_cast(float, (u32)h << 16);
}
__device__ __forceinline__ u16 f2h(float f) {
  _Float16 h = (_Float16)f;
  return __builtin_bit_cast(u16, h);
}
// packed f32x2 -> bf16x2 (T12; single instruction, RNE)
__device__ __forceinline__ u32 cvtpk(float a, float b) {
  u32 r;
  asm("v_cvt_pk_bf16_f32 %0, %1, %2" : "=v"(r) : "v"(a), "v"(b));
  return r;  // a low16, b high16
}
// v_permlane32_swap_b32 a, b: a' = {lo: a_lo, hi: b_lo}; b' = {lo: a_hi, hi: b_hi}
__device__ __forceinline__ void plswap(u32& a, u32& b) {
  asm volatile("v_permlane32_swap_b32 %0, %1" : "+v"(a), "+v"(b));
}
__device__ __forceinline__ void mfma16(f32x4& d, u32x4 a, u32x4 b) {
  asm volatile("v_mfma_f32_16x16x32_bf16 %0, %1, %2, %0"
               : "+v"(d)
               : "v"(a), "v"(b));
}
__device__ __forceinline__ void mfma16f(f32x4& d, u32x4 a, u32x4 b) {
  asm volatile("v_mfma_f32_16x16x32_f16 %0, %1, %2, %0"
               : "+v"(d)
               : "v"(a), "v"(b));
}
__device__ __forceinline__ void mfma32(f32x16& d, u32x4 a, u32x4 b) {
  asm volatile("v_mfma_f32_32x32x16_bf16 %0, %1, %2, %0"
               : "+v"(d)
               : "v"(a), "v"(b));
}
// async global->LDS, 16B per lane; lds dest = wave-uniform base (+lane*16 by HW)
__device__ __forceinline__ void gld16(const void* g, void* l) {
  __builtin_amdgcn_global_load_lds(
      (const __attribute__((address_space(1))) void*)(void*)g,
      (__attribute__((address_space(3))) void*)l, 16, 0, 0);
}
// MFMA->VALU read hazard fence + scheduling pin (rule #18)
#define HZ()                                            \
  do {                                                  \
    asm volatile("s_nop 7\ns_nop 7\ns_nop 7\ns_nop 7"); \
    __builtin_amdgcn_sched_barrier(0);                  \
  } while (0)
// RAW workgroup barrier (no implicit vmcnt(0) drain; HK protocol, r15-proven)
#define BAR()                          \
  do {                                 \
    __builtin_amdgcn_s_barrier();      \
    __builtin_amdgcn_sched_barrier(0); \
  } while (0)

// ============================================================================
// prep: rope table + bf16/fp16 converts, fused (one launch).
// ============================================================================
__global__ __launch_bounds__(256) void prep_kernel(
    const float* __restrict__ x, const float* __restrict__ w1,
    const float* __restrict__ w2, float2* __restrict__ tab,
    u16* __restrict__ xbf, u16* __restrict__ w1bf, u16* __restrict__ w2h) {
  const int blk = blockIdx.x;
  const int t = threadIdx.x;
  if (blk < 256) {
    const int idx = (blk << 8) + t;
    const int s = idx >> 5, i = idx & 31;
    double theta = pow(10000.0, -((double)(2 * i)) / 64.0);
    float ang = (float)s * (float)theta;
    tab[idx] = make_float2(cosf(ang), sinf(ang));
  } else if (blk < 1280) {
    int i = ((blk - 256) << 8) + t;
#pragma unroll
    for (int r = 0; r < 4; ++r, i += 262144) {
      float4 v = ((const float4*)x)[i];
      ushort4 o;
      o.x = f2bf(v.x); o.y = f2bf(v.y); o.z = f2bf(v.z); o.w = f2bf(v.w);
      ((ushort4*)xbf)[i] = o;
    }
  } else if (blk < 2048) {
    int i = ((blk - 1280) << 8) + t;
#pragma unroll
    for (int r = 0; r < 4; ++r, i += 196608) {
      float4 v = ((const float4*)w1)[i];
      ushort4 o;
      o.x = f2bf(v.x); o.y = f2bf(v.y); o.z = f2bf(v.z); o.w = f2bf(v.w);
      ((ushort4*)w1bf)[i] = o;
    }
  } else {
    int i = ((blk - 2048) << 8) + t;
#pragma unroll
    for (int r = 0; r < 4; ++r, i += 65536) {
      float4 v = ((const float4*)w2)[i];
      ushort4 o;
      o.x = f2h(v.x); o.y = f2h(v.y); o.z = f2h(v.z); o.w = f2h(v.w);
      ((ushort4*)w2h)[i] = o;
    }
  }
}

// ============================================================================
// B^T GEMM: 128 x (NI*32) tile, BK=64, 4 waves (2x2), gld_lds staging, T1
// XCD-swizzled grid. NI=4 -> 128x128; NI=2 -> 128x64.
// MODE 0 (bf16, NI=4): q/k -> RoPE scatter; V -> LDS-transposed coalesced V^T.
// MODE 1 (fp16, NI=2): single pass, f32 stores.
// ============================================================================
template <int MODE, int NI>
__global__ __launch_bounds__(256) void gemm_bt(
    const u16* __restrict__ Ahi, const u16* __restrict__ Bhi, int nbn, int nkb,
    int cpx, const float2* __restrict__ tab, u16* __restrict__ qd,
    u16* __restrict__ kd, u16* __restrict__ vtd, float* __restrict__ fout) {
  __shared__ __align__(16) char SMEM[MODE == 0 ? 34816 : 16384 + NI * 4096];
  char* As = SMEM;
  char* Bs = SMEM + 16384;
  const int bid = blockIdx.x;
  const int wgid = (bid & 7) * cpx + (bid >> 3);  // T1 XCD remap (nwg%8==0)
  const int bm = wgid / nbn;
  const int bn = wgid % nbn;
  const int m0 = bm << 7;
  const int n0 = bn * (NI << 5);
  const int t = threadIdx.x;
  const int w = t >> 6;
  const int lane = t & 63;
  const int lr = lane & 15;
  const int lg = lane >> 4;
  const int wr0 = (w >> 1) << 6;
  const int wc0 = (w & 1) * (NI << 4);
  const int srow0 = t >> 3;
  const int sblk = t & 7;

  f32x4 acc[4][NI];
#pragma unroll
  for (int mi = 0; mi < 4; ++mi)
#pragma unroll
    for (int ni = 0; ni < NI; ++ni) acc[mi][ni] = (f32x4)0.0f;

  for (int kb = 0; kb < nkb; ++kb) {
    const int k0 = kb << 6;
    if (kb) __syncthreads();
#pragma unroll
    for (int r = 0; r < 4; ++r) {
      const int row = srow0 + (r << 5);
      const int g = sblk ^ (row & 7);
      gld16(Ahi + (size_t)(m0 + row) * 1024 + k0 + (g << 3),
            As + (r << 12) + (w << 10));
    }
#pragma unroll
    for (int r = 0; r < NI; ++r) {
      const int row = srow0 + (r << 5);
      const int g = sblk ^ (row & 7);
      gld16(Bhi + (size_t)(n0 + row) * 1024 + k0 + (g << 3),
            Bs + (r << 12) + (w << 10));
    }
    asm volatile("s_waitcnt vmcnt(0)" ::: "memory");
    __syncthreads();
#pragma unroll
    for (int kk = 0; kk < 2; ++kk) {
      u32x4 af[4], bf[NI];
#pragma unroll
      for (int mi = 0; mi < 4; ++mi) {
        const int row = wr0 + (mi << 4) + lr;
        af[mi] = *(const u32x4*)(As + row * 128 +
                                 ((((kk << 2) + lg) ^ (row & 7)) << 4));
      }
#pragma unroll
      for (int ni = 0; ni < NI; ++ni) {
        const int row = wc0 + (ni << 4) + lr;
        bf[ni] = *(const u32x4*)(Bs + row * 128 +
                                 ((((kk << 2) + lg) ^ (row & 7)) << 4));
      }
      asm volatile("s_nop 1");
      __builtin_amdgcn_s_setprio(1);
#pragma unroll
      for (int mi = 0; mi < 4; ++mi)
#pragma unroll
        for (int ni = 0; ni < NI; ++ni) {
          if constexpr (MODE == 1)
            mfma16f(acc[mi][ni], af[mi], bf[ni]);
          else
            mfma16(acc[mi][ni], af[mi], bf[ni]);
        }
      __builtin_amdgcn_s_setprio(0);
    }
  }
  HZ();
  if constexpr (MODE == 0) {
    if (n0 >= 2048) {
      // ---- V path: LDS transpose -> coalesced V^T stores ----
      u16* Vt = (u16*)SMEM;
      __syncthreads();  // all waves done reading As/Bs before overlay write
#pragma unroll
      for (int mi = 0; mi < 4; ++mi)
#pragma unroll
        for (int ni = 0; ni < NI; ++ni)
#pragma unroll
          for (int i = 0; i < 4; ++i) {
            const int dl = wc0 + (ni << 4) + lr;
            const int sl = wr0 + (mi << 4) + (lg << 2) + i;
            Vt[dl * 136 + sl] = f2bf(acc[mi][ni][i]);
          }
      __syncthreads();
      const int row = t >> 1;
      const int half = t & 1;
      const int hh2 = (n0 - 2048 + row) >> 6;
      const int d2 = (n0 - 2048 + row) & 63;
      const int b2 = m0 >> 11;
      u16* dst = vtd + (((size_t)(b2 * 16 + hh2) * 64 + d2) * 2048) +
                 (m0 & 2047) + half * 64;
      const u16* src = Vt + row * 136 + half * 64;
#pragma unroll
      for (int c = 0; c < 8; ++c)
        *(u32x4*)(dst + (c << 3)) = *(const u32x4*)(src + (c << 3));
      return;
    }
  }
#pragma unroll
  for (int mi = 0; mi < 4; ++mi)
#pragma unroll
    for (int ni = 0; ni < NI; ++ni)
#pragma unroll
      for (int i = 0; i < 4; ++i) {
        float val = acc[mi][ni][i];
        const int grow = m0 + wr0 + (mi << 4) + (lg << 2) + i;
        const int col = n0 + wc0 + (ni << 4) + lr;
        if (MODE == 0) {
          const int b = grow >> 11, s = grow & 2047;
          const int which = col >> 10, hh = (col >> 6) & 15, d = col & 63;
          const size_t base = (size_t)((b << 4) + hh);
          float other = __shfl_xor(val, 1);
          float2 cs = tab[(s << 5) + (d >> 1)];
          float r = (d & 1) ? fmaf(val, cs.x, other * cs.y)
                            : fmaf(val, cs.x, -other * cs.y);
          // fold (1/sqrt(HD)) * log2(e) into q -> softmax in exp2 domain
          if (which == 0) r *= 0.18033688011f;
          u16* dstp = which ? kd : qd;
          dstp[(base * 2048 + s) * 64 + d] = f2bf(r);
        } else {
          fout[(size_t)grow * 1024 + col] = val;
        }
      }
}

// ============================================================================
// Flash attention v9 = v7 + KVBLK=128: one barrier-pair + one HZ per 128 j
// (halves sync count), lsum as 8-way ILP tree (removes the serial add chain
// from the critical path), V LDS rows 256B = 16 chunks -> XOR (row&15) drops
// V-read bank conflicts 4-way -> 2-way (free per m136). Dbuf 2x32KB = 64KB,
// 2 blocks/CU. Fixed-max exp2 softmax (bounded; r11 derivation).
// 1 block = (b,h,128 q rows) = 4 waves x 32; grid 512.
// ============================================================================
__global__ __launch_bounds__(256) void attn_mfma(
    const u16* __restrict__ q, const u16* __restrict__ k,
    const u16* __restrict__ vt, u16* __restrict__ o16) {
  __shared__ __align__(16) char Ks[2][16384];  // [128 j][64 d], XOR (row&7)
  __shared__ __align__(16) char Vs[2][16384];  // [64 dd][128 j], XOR (row&15)
  const int bid = blockIdx.x;
  const int swz = (bid & 7) * 64 + (bid >> 3);  // XCD remap (512%8==0)
  const int qt = swz & 15;
  const int hh = (swz >> 4) & 15;
  const int b = swz >> 8;
  const int t = threadIdx.x;
  const int w = t >> 6;
  const int lane = t & 63;
  const int lq = lane & 31;  // q col / j row / dd row within 32
  const int h = lane >> 5;   // lane half

  const size_t bh = (size_t)((b << 4) + hh);
  const u16* qb = q + (bh * 2048 + (size_t)(qt * 128 + w * 32)) * 64;
  const u16* kb = k + bh * 2048 * 64;
  const u16* vb = vt + bh * 64 * 2048;

  // Q B-frags: col q=lq, d slots = dk*16 + 8*h + 0..7
  u32x4 qf[4];
#pragma unroll
  for (int dk = 0; dk < 4; ++dk)
    qf[dk] = *(const u32x4*)(qb + lq * 64 + dk * 16 + h * 8);

  // stage one 128-j tile: K 16KB (128 rows x 8 chunks) + V 16KB (64 x 16)
  auto issue = [&](int kt_, int buf_) {
    const u16* ksrc = kb + (size_t)kt_ * 8192;
#pragma unroll
    for (int r = 0; r < 4; ++r) {
      const int ci = (r << 8) + (w << 6) + lane;
      const int dstb = ((r << 8) + (w << 6)) << 4;  // wave-uniform
      {
        const int row = ci >> 3, ch = ci & 7;
        const int g = ch ^ (row & 7);
        gld16(ksrc + row * 64 + (g << 3), &Ks[buf_][dstb]);
      }
      {
        const int row = ci >> 4, ch = ci & 15;
        const int g = ch ^ (row & 15);
        gld16(vb + (size_t)row * 2048 + kt_ * 128 + (g << 3), &Vs[buf_][dstb]);
      }
    }
  };

  f32x16 oacc0 = (f32x16)0.0f, oacc1 = (f32x16)0.0f;
  float lrow = 0.0f;  // lane-half partial row sum; combined in epilogue

// exp2 all 16 then 8-way-ILP tree sum into lrow
#define EXPTREE(S)                                                            \
  {                                                                           \
    _Pragma("unroll") for (int i = 0; i < 16; ++i) S[i] = EXP2(S[i]);         \
    float a0 = (S[0] + S[1]) + (S[2] + S[3]);                                 \
    float a1 = (S[4] + S[5]) + (S[6] + S[7]);                                 \
    float a2 = (S[8] + S[9]) + (S[10] + S[11]);                               \
    float a3 = (S[12] + S[13]) + (S[14] + S[15]);                             \
    lrow += (a0 + a1) + (a2 + a3);                                            \
  }

// T12 pack of one 64-j half (S0 = j-block lo32, S1 = hi32) into pa0..pa3
#define PACK(S0, S1)                                                          \
  {                                                                           \
    u32 w0 = cvtpk(S0[0], S0[1]), w1 = cvtpk(S0[2], S0[3]);                   \
    u32 w2 = cvtpk(S0[4], S0[5]), w3 = cvtpk(S0[6], S0[7]);                   \
    u32 w4 = cvtpk(S0[8], S0[9]), w5 = cvtpk(S0[10], S0[11]);                 \
    u32 w6 = cvtpk(S0[12], S0[13]), w7 = cvtpk(S0[14], S0[15]);               \
    plswap(w0, w2);                                                           \
    plswap(w1, w3);                                                           \
    plswap(w4, w6);                                                           \
    plswap(w5, w7);                                                           \
    pa0[0] = w0; pa0[1] = w1; pa0[2] = w2; pa0[3] = w3;                       \
    pa1[0] = w4; pa1[1] = w5; pa1[2] = w6; pa1[3] = w7;                       \
    u32 y0 = cvtpk(S1[0], S1[1]), y1 = cvtpk(S1[2], S1[3]);                   \
    u32 y2 = cvtpk(S1[4], S1[5]), y3 = cvtpk(S1[6], S1[7]);                   \
    u32 y4 = cvtpk(S1[8], S1[9]), y5 = cvtpk(S1[10], S1[11]);                 \
    u32 y6 = cvtpk(S1[12], S1[13]), y7 = cvtpk(S1[14], S1[15]);               \
    plswap(y0, y2);                                                           \
    plswap(y1, y3);                                                           \
    plswap(y4, y6);                                                           \
    plswap(y5, y7);                                                           \
    pa2[0] = y0; pa2[1] = y1; pa2[2] = y2; pa2[3] = y3;                       \
    pa3[0] = y4; pa3[1] = y5; pa3[2] = y6; pa3[3] = y7;                       \
  }

// PV over one 64-j half; JB = V chunk base (0 for j 0..63, 8 for 64..127)
#define PVH(VCUR, JB)                                                         \
  asm volatile("s_nop 2");                                                    \
  __builtin_amdgcn_s_setprio(1);                                              \
  {                                                                           \
    u32x4 vf0, vf1;                                                           \
    _Pragma("unroll") for (int kbk = 0; kbk < 4; ++kbk) {                     \
      const int jc = (JB) + (kbk << 1) + h;                                   \
      const int co = (jc ^ (lq & 15)) << 4;                                   \
      vf0 = *(const u32x4*)((VCUR) + lq * 256 + co);                          \
      vf1 = *(const u32x4*)((VCUR) + (32 + lq) * 256 + co);                   \
      if (kbk == 0) { mfma32(oacc0, pa0, vf0); mfma32(oacc1, pa0, vf1); }     \
      if (kbk == 1) { mfma32(oacc0, pa1, vf0); mfma32(oacc1, pa1, vf1); }     \
      if (kbk == 2) { mfma32(oacc0, pa2, vf0); mfma32(oacc1, pa2, vf1); }     \
      if (kbk == 3) { mfma32(oacc0, pa3, vf0); mfma32(oacc1, pa3, vf1); }     \
    }                                                                         \
  }                                                                           \
  __builtin_amdgcn_s_setprio(0);

  issue(0, 0);
  for (int kt = 0; kt < 16; ++kt) {
    const int cur = kt & 1;
    if (kt < 15) {
      issue(kt + 1, cur ^ 1);
      asm volatile("s_waitcnt vmcnt(8)" ::: "memory");  // own kt loads landed
    } else {
      asm volatile("s_waitcnt vmcnt(0)" ::: "memory");
    }
    BAR();
    const char* Kc = Ks[cur];
    const char* Vc = Vs[cur];
    // S^T: 4 j-blocks of 32 rows, cols q
    f32x16 s0 = (f32x16)0.0f, s1 = (f32x16)0.0f;
    f32x16 s2 = (f32x16)0.0f, s3 = (f32x16)0.0f;
    __builtin_amdgcn_s_setprio(1);
#pragma unroll
    for (int dk = 0; dk < 4; ++dk) {
      const int co = ((((dk << 1) + h) ^ (lq & 7)) << 4);
      u32x4 kf0 = *(const u32x4*)(Kc + lq * 128 + co);
      u32x4 kf1 = *(const u32x4*)(Kc + (32 + lq) * 128 + co);
      u32x4 kf2 = *(const u32x4*)(Kc + (64 + lq) * 128 + co);
      u32x4 kf3 = *(const u32x4*)(Kc + (96 + lq) * 128 + co);
      mfma32(s0, kf0, qf[dk]);
      mfma32(s1, kf1, qf[dk]);
      mfma32(s2, kf2, qf[dk]);
      mfma32(s3, kf3, qf[dk]);
    }
    __builtin_amdgcn_s_setprio(0);
    HZ();
    EXPTREE(s0)
    EXPTREE(s1)
    {
      u32x4 pa0, pa1, pa2, pa3;
      PACK(s0, s1)
      PVH(Vc, 0)
    }
    EXPTREE(s2)
    EXPTREE(s3)
    {
      u32x4 pa0, pa1, pa2, pa3;
      PACK(s2, s3)
      PVH(Vc, 8)
    }
    BAR();
  }
#undef PVH
#undef PACK
#undef EXPTREE
  HZ();
  // epilogue: combine lane-half l, normalize, fp16 store
  const float invl = 1.0f / (lrow + __shfl_xor(lrow, 32));
#pragma unroll
  for (int r = 0; r < 16; ++r) {
    const int qr = (r & 3) + 8 * (r >> 2) + 4 * h;
    const float fr = __shfl(invl, qr);
    const size_t srow = (size_t)(b * 2048 + (qt << 7) + (w << 5) + qr);
    const size_t base = srow * 1024 + (hh << 6) + lq;
    o16[base] = f2h(oacc0[r] * fr);
    o16[base + 32] = f2h(oacc1[r] * fr);
  }
}

extern "C" void kernel_launch(void* const* d_in, const int* in_sizes, int n_in,
                              void* d_out, int out_size, void* d_ws,
                              size_t ws_size, hipStream_t stream) {
  const float* x = (const float*)d_in[0];
  const float* w1 = (const float*)d_in[1];
  const float* w2 = (const float*)d_in[2];
  char* ws = (char*)d_ws;
  float2* tab = (float2*)(ws + TAB_B);
  u16* qbf = (u16*)(ws + QBF_B);
  u16* kbf = (u16*)(ws + KBF_B);
  u16* vtbf = (u16*)(ws + VTB_B);
  u16* w2h = (u16*)(ws + W2H_B);
  u16* xbf = (u16*)(ws + XBF_B);
  u16* w1bf = (u16*)(ws + W1BF_B);
  u16* o16 = (u16*)(ws + O16_B);
  float* out = (float*)d_out;

  prep_kernel<<<dim3(2304), dim3(256), 0, stream>>>(x, w1, w2, tab, xbf, w1bf,
                                                    w2h);
  gemm_bt<0, 4><<<dim3(32 * 24), dim3(256), 0, stream>>>(
      xbf, w1bf, 24, 16, 96, tab, qbf, kbf, vtbf, nullptr);
  attn_mfma<<<dim3(512), dim3(256), 0, stream>>>(qbf, kbf, vtbf, o16);
  gemm_bt<1, 2><<<dim3(32 * 16), dim3(256), 0, stream>>>(
      o16, w2h, 16, 16, 64, nullptr, nullptr, nullptr, nullptr, out);
}

// Round 19
// 105.583 us; speedup vs baseline: 1.0032x; 1.0032x over previous
//
#include <hip/hip_runtime.h>
#include <math.h>

typedef unsigned short u16;
typedef unsigned int u32;
typedef float f32x4 __attribute__((ext_vector_type(4)));
typedef float f32x16 __attribute__((ext_vector_type(16)));
typedef u32 u32x4 __attribute__((ext_vector_type(4)));

// ---- problem dims: B=2 S=2048 E=1024 H=16 HD=64 ----
static const size_t TAB_B  = 0;         // float2[2048][32]
static const size_t QBF_B  = 524288;    // bf16 [2][16][2048][64], pre-scaled 0.125*log2e
static const size_t KBF_B  = 8912896;   // bf16 [2][16][2048][64]
static const size_t VTB_B  = 17301504;  // bf16 [2][16][64][2048]  (V transposed)
static const size_t W2H_B  = 25690112;  // fp16 [1024][1024]
static const size_t XBF_B  = 29884416;  // bf16 x      (dead after QKV gemm)
static const size_t W1BF_B = 38273024;  // bf16 w1     (dead after QKV gemm)
static const size_t O16_B  = 29884416;  // fp16 [4096][1024], reuses XBF

#if __has_builtin(__builtin_amdgcn_exp2f)
#define EXP2(x) __builtin_amdgcn_exp2f(x)
#else
#define EXP2(x) __expf(0.69314718056f * (x))
#endif

__device__ __forceinline__ u16 f2bf(float f) {
  u32 u = __builtin_bit_cast(u32, f);
  u += 0x7fffu + ((u >> 16) & 1u);
  return (u16)(u >> 16);
}
__device__ __forceinline__ float bf2f(u16 h) {
  return __builtin_bit_cast(float, (u32)h << 16);
}
__device__ __forceinline__ u16 f2h(float f) {
  _Float16 h = (_Float16)f;
  return __builtin_bit_cast(u16, h);
}
// packed f32x2 -> bf16x2 (T12; single instruction, RNE)
__device__ __forceinline__ u32 cvtpk(float a, float b) {
  u32 r;
  asm("v_cvt_pk_bf16_f32 %0, %1, %2" : "=v"(r) : "v"(a), "v"(b));
  return r;  // a low16, b high16
}
// v_permlane32_swap_b32 a, b: a' = {lo: a_lo, hi: b_lo}; b' = {lo: a_hi, hi: b_hi}
__device__ __forceinline__ void plswap(u32& a, u32& b) {
  asm volatile("v_permlane32_swap_b32 %0, %1" : "+v"(a), "+v"(b));
}
__device__ __forceinline__ void mfma16(f32x4& d, u32x4 a, u32x4 b) {
  asm volatile("v_mfma_f32_16x16x32_bf16 %0, %1, %2, %0"
               : "+v"(d)
               : "v"(a), "v"(b));
}
__device__ __forceinline__ void mfma16f(f32x4& d, u32x4 a, u32x4 b) {
  asm volatile("v_mfma_f32_16x16x32_f16 %0, %1, %2, %0"
               : "+v"(d)
               : "v"(a), "v"(b));
}
__device__ __forceinline__ void mfma32(f32x16& d, u32x4 a, u32x4 b) {
  asm volatile("v_mfma_f32_32x32x16_bf16 %0, %1, %2, %0"
               : "+v"(d)
               : "v"(a), "v"(b));
}
// async global->LDS, 16B per lane; lds dest = wave-uniform base (+lane*16 by HW)
__device__ __forceinline__ void gld16(const void* g, void* l) {
  __builtin_amdgcn_global_load_lds(
      (const __attribute__((address_space(1))) void*)(void*)g,
      (__attribute__((address_space(3))) void*)l, 16, 0, 0);
}
// MFMA->VALU read hazard fence + scheduling pin (rule #18)
#define HZ()                                            \
  do {                                                  \
    asm volatile("s_nop 7\ns_nop 7\ns_nop 7\ns_nop 7"); \
    __builtin_amdgcn_sched_barrier(0);                  \
  } while (0)
// RAW workgroup barrier (no implicit vmcnt(0) drain; HK protocol, r15-proven)
#define BAR()                          \
  do {                                 \
    __builtin_amdgcn_s_barrier();      \
    __builtin_amdgcn_sched_barrier(0); \
  } while (0)

// ============================================================================
// prep: rope table + bf16/fp16 converts, fused (one launch).
// ============================================================================
__global__ __launch_bounds__(256) void prep_kernel(
    const float* __restrict__ x, const float* __restrict__ w1,
    const float* __restrict__ w2, float2* __restrict__ tab,
    u16* __restrict__ xbf, u16* __restrict__ w1bf, u16* __restrict__ w2h) {
  const int blk = blockIdx.x;
  const int t = threadIdx.x;
  if (blk < 256) {
    const int idx = (blk << 8) + t;
    const int s = idx >> 5, i = idx & 31;
    double theta = pow(10000.0, -((double)(2 * i)) / 64.0);
    float ang = (float)s * (float)theta;
    tab[idx] = make_float2(cosf(ang), sinf(ang));
  } else if (blk < 1280) {
    int i = ((blk - 256) << 8) + t;
#pragma unroll
    for (int r = 0; r < 4; ++r, i += 262144) {
      float4 v = ((const float4*)x)[i];
      ushort4 o;
      o.x = f2bf(v.x); o.y = f2bf(v.y); o.z = f2bf(v.z); o.w = f2bf(v.w);
      ((ushort4*)xbf)[i] = o;
    }
  } else if (blk < 2048) {
    int i = ((blk - 1280) << 8) + t;
#pragma unroll
    for (int r = 0; r < 4; ++r, i += 196608) {
      float4 v = ((const float4*)w1)[i];
      ushort4 o;
      o.x = f2bf(v.x); o.y = f2bf(v.y); o.z = f2bf(v.z); o.w = f2bf(v.w);
      ((ushort4*)w1bf)[i] = o;
    }
  } else {
    int i = ((blk - 2048) << 8) + t;
#pragma unroll
    for (int r = 0; r < 4; ++r, i += 65536) {
      float4 v = ((const float4*)w2)[i];
      ushort4 o;
      o.x = f2h(v.x); o.y = f2h(v.y); o.z = f2h(v.z); o.w = f2h(v.w);
      ((ushort4*)w2h)[i] = o;
    }
  }
}

// ============================================================================
// B^T GEMM: 128 x (NI*32) tile, BK=64, 4 waves (2x2), gld_lds staging, T1
// XCD-swizzled grid. NI=4 -> 128x128; NI=2 -> 128x64.
// MODE 0 (bf16, NI=4): q/k -> RoPE scatter; V -> LDS-transposed coalesced V^T.
// MODE 1 (fp16, NI=2): single pass, f32 stores.
// ============================================================================
template <int MODE, int NI>
__global__ __launch_bounds__(256) void gemm_bt(
    const u16* __restrict__ Ahi, const u16* __restrict__ Bhi, int nbn, int nkb,
    int cpx, const float2* __restrict__ tab, u16* __restrict__ qd,
    u16* __restrict__ kd, u16* __restrict__ vtd, float* __restrict__ fout) {
  __shared__ __align__(16) char SMEM[MODE == 0 ? 34816 : 16384 + NI * 4096];
  char* As = SMEM;
  char* Bs = SMEM + 16384;
  const int bid = blockIdx.x;
  const int wgid = (bid & 7) * cpx + (bid >> 3);  // T1 XCD remap (nwg%8==0)
  const int bm = wgid / nbn;
  const int bn = wgid % nbn;
  const int m0 = bm << 7;
  const int n0 = bn * (NI << 5);
  const int t = threadIdx.x;
  const int w = t >> 6;
  const int lane = t & 63;
  const int lr = lane & 15;
  const int lg = lane >> 4;
  const int wr0 = (w >> 1) << 6;
  const int wc0 = (w & 1) * (NI << 4);
  const int srow0 = t >> 3;
  const int sblk = t & 7;

  f32x4 acc[4][NI];
#pragma unroll
  for (int mi = 0; mi < 4; ++mi)
#pragma unroll
    for (int ni = 0; ni < NI; ++ni) acc[mi][ni] = (f32x4)0.0f;

  for (int kb = 0; kb < nkb; ++kb) {
    const int k0 = kb << 6;
    if (kb) __syncthreads();
#pragma unroll
    for (int r = 0; r < 4; ++r) {
      const int row = srow0 + (r << 5);
      const int g = sblk ^ (row & 7);
      gld16(Ahi + (size_t)(m0 + row) * 1024 + k0 + (g << 3),
            As + (r << 12) + (w << 10));
    }
#pragma unroll
    for (int r = 0; r < NI; ++r) {
      const int row = srow0 + (r << 5);
      const int g = sblk ^ (row & 7);
      gld16(Bhi + (size_t)(n0 + row) * 1024 + k0 + (g << 3),
            Bs + (r << 12) + (w << 10));
    }
    asm volatile("s_waitcnt vmcnt(0)" ::: "memory");
    __syncthreads();
#pragma unroll
    for (int kk = 0; kk < 2; ++kk) {
      u32x4 af[4], bf[NI];
#pragma unroll
      for (int mi = 0; mi < 4; ++mi) {
        const int row = wr0 + (mi << 4) + lr;
        af[mi] = *(const u32x4*)(As + row * 128 +
                                 ((((kk << 2) + lg) ^ (row & 7)) << 4));
      }
#pragma unroll
      for (int ni = 0; ni < NI; ++ni) {
        const int row = wc0 + (ni << 4) + lr;
        bf[ni] = *(const u32x4*)(Bs + row * 128 +
                                 ((((kk << 2) + lg) ^ (row & 7)) << 4));
      }
      asm volatile("s_nop 1");
      __builtin_amdgcn_s_setprio(1);
#pragma unroll
      for (int mi = 0; mi < 4; ++mi)
#pragma unroll
        for (int ni = 0; ni < NI; ++ni) {
          if constexpr (MODE == 1)
            mfma16f(acc[mi][ni], af[mi], bf[ni]);
          else
            mfma16(acc[mi][ni], af[mi], bf[ni]);
        }
      __builtin_amdgcn_s_setprio(0);
    }
  }
  HZ();
  if constexpr (MODE == 0) {
    if (n0 >= 2048) {
      // ---- V path: LDS transpose -> coalesced V^T stores ----
      u16* Vt = (u16*)SMEM;
      __syncthreads();  // all waves done reading As/Bs before overlay write
#pragma unroll
      for (int mi = 0; mi < 4; ++mi)
#pragma unroll
        for (int ni = 0; ni < NI; ++ni)
#pragma unroll
          for (int i = 0; i < 4; ++i) {
            const int dl = wc0 + (ni << 4) + lr;
            const int sl = wr0 + (mi << 4) + (lg << 2) + i;
            Vt[dl * 136 + sl] = f2bf(acc[mi][ni][i]);
          }
      __syncthreads();
      const int row = t >> 1;
      const int half = t & 1;
      const int hh2 = (n0 - 2048 + row) >> 6;
      const int d2 = (n0 - 2048 + row) & 63;
      const int b2 = m0 >> 11;
      u16* dst = vtd + (((size_t)(b2 * 16 + hh2) * 64 + d2) * 2048) +
                 (m0 & 2047) + half * 64;
      const u16* src = Vt + row * 136 + half * 64;
#pragma unroll
      for (int c = 0; c < 8; ++c)
        *(u32x4*)(dst + (c << 3)) = *(const u32x4*)(src + (c << 3));
      return;
    }
  }
#pragma unroll
  for (int mi = 0; mi < 4; ++mi)
#pragma unroll
    for (int ni = 0; ni < NI; ++ni)
#pragma unroll
      for (int i = 0; i < 4; ++i) {
        float val = acc[mi][ni][i];
        const int grow = m0 + wr0 + (mi << 4) + (lg << 2) + i;
        const int col = n0 + wc0 + (ni << 4) + lr;
        if (MODE == 0) {
          const int b = grow >> 11, s = grow & 2047;
          const int which = col >> 10, hh = (col >> 6) & 15, d = col & 63;
          const size_t base = (size_t)((b << 4) + hh);
          float other = __shfl_xor(val, 1);
          float2 cs = tab[(s << 5) + (d >> 1)];
          float r = (d & 1) ? fmaf(val, cs.x, other * cs.y)
                            : fmaf(val, cs.x, -other * cs.y);
          // fold (1/sqrt(HD)) * log2(e) into q -> softmax in exp2 domain
          if (which == 0) r *= 0.18033688011f;
          u16* dstp = which ? kd : qd;
          dstp[(base * 2048 + s) * 64 + d] = f2bf(r);
        } else {
          fout[(size_t)grow * 1024 + col] = val;
        }
      }
}

// ============================================================================
// Flash attention v11 = r17's proven per-wave body (V back in LDS — direct
// global V loads are forbidden: 2x unexplained HW failures r7/r18) with
// Q-TILE 256 (HK ts_qo): 8 waves x 32 q rows, 512 threads, grid 256 = 1
// block/CU (tail-free). Halves ALL staging per q-row (global fetch, gld16,
// LDS writes) vs q-tile 128 — the r10/r11 A/B measured staging at ~13.5us/1x.
// KVBLK=128 dbuf (K 2x16KB + V 2x16KB = 64KB), counted vmcnt(4), raw BARs.
// Fixed-max exp2 softmax (bounded; r11 derivation).
// ============================================================================
__global__ __launch_bounds__(512) void attn_mfma(
    const u16* __restrict__ q, const u16* __restrict__ k,
    const u16* __restrict__ vt, u16* __restrict__ o16) {
  __shared__ __align__(16) char Ks[2][16384];  // [128 j][64 d], XOR (row&7)
  __shared__ __align__(16) char Vs[2][16384];  // [64 dd][128 j], XOR (row&15)
  const int bid = blockIdx.x;
  const int swz = (bid & 7) * 32 + (bid >> 3);  // XCD remap (256%8==0)
  const int qt = swz & 7;                        // 8 q-tiles of 256 rows
  const int hh = (swz >> 3) & 15;
  const int b = swz >> 7;
  const int t = threadIdx.x;  // 0..511
  const int w = t >> 6;       // 8 waves
  const int lane = t & 63;
  const int lq = lane & 31;  // q col / j row / dd row within 32
  const int h = lane >> 5;   // lane half

  const size_t bh = (size_t)((b << 4) + hh);
  const u16* qb = q + (bh * 2048 + (size_t)(qt * 256 + w * 32)) * 64;
  const u16* kb = k + bh * 2048 * 64;
  const u16* vb = vt + bh * 64 * 2048;

  // Q B-frags: col q=lq, d slots = dk*16 + 8*h + 0..7
  u32x4 qf[4];
#pragma unroll
  for (int dk = 0; dk < 4; ++dk)
    qf[dk] = *(const u32x4*)(qb + lq * 64 + dk * 16 + h * 8);

  // stage one 128-j tile: K 16KB (128r x 8c) + V 16KB (64r x 16c); 512 thr x
  // 2 rounds x {K,V} = 4 gld16/thread
  auto issue = [&](int kt_, int buf_) {
    const u16* ksrc = kb + (size_t)kt_ * 8192;
#pragma unroll
    for (int r = 0; r < 2; ++r) {
      const int ci = (r << 9) + (w << 6) + lane;
      const int dstb = ((r << 9) + (w << 6)) << 4;  // wave-uniform
      {
        const int row = ci >> 3, ch = ci & 7;
        const int g = ch ^ (row & 7);
        gld16(ksrc + row * 64 + (g << 3), &Ks[buf_][dstb]);
      }
      {
        const int row = ci >> 4, ch = ci & 15;
        const int g = ch ^ (row & 15);
        gld16(vb + (size_t)row * 2048 + kt_ * 128 + (g << 3), &Vs[buf_][dstb]);
      }
    }
  };

  f32x16 oacc0 = (f32x16)0.0f, oacc1 = (f32x16)0.0f;
  float lrow = 0.0f;  // lane-half partial row sum; combined in epilogue

// exp2 all 16 then 8-way-ILP tree sum into lrow
#define EXPTREE(S)                                                            \
  {                                                                           \
    _Pragma("unroll") for (int i = 0; i < 16; ++i) S[i] = EXP2(S[i]);         \
    float a0 = (S[0] + S[1]) + (S[2] + S[3]);                                 \
    float a1 = (S[4] + S[5]) + (S[6] + S[7]);                                 \
    float a2 = (S[8] + S[9]) + (S[10] + S[11]);                               \
    float a3 = (S[12] + S[13]) + (S[14] + S[15]);                             \
    lrow += (a0 + a1) + (a2 + a3);                                            \
  }

// T12 pack of one 64-j half (S0 = j-block lo32, S1 = hi32) into pa0..pa3
#define PACK(S0, S1)                                                          \
  {                                                                           \
    u32 w0 = cvtpk(S0[0], S0[1]), w1 = cvtpk(S0[2], S0[3]);                   \
    u32 w2 = cvtpk(S0[4], S0[5]), w3 = cvtpk(S0[6], S0[7]);                   \
    u32 w4 = cvtpk(S0[8], S0[9]), w5 = cvtpk(S0[10], S0[11]);                 \
    u32 w6 = cvtpk(S0[12], S0[13]), w7 = cvtpk(S0[14], S0[15]);               \
    plswap(w0, w2);                                                           \
    plswap(w1, w3);                                                           \
    plswap(w4, w6);                                                           \
    plswap(w5, w7);                                                           \
    pa0[0] = w0; pa0[1] = w1; pa0[2] = w2; pa0[3] = w3;                       \
    pa1[0] = w4; pa1[1] = w5; pa1[2] = w6; pa1[3] = w7;                       \
    u32 y0 = cvtpk(S1[0], S1[1]), y1 = cvtpk(S1[2], S1[3]);                   \
    u32 y2 = cvtpk(S1[4], S1[5]), y3 = cvtpk(S1[6], S1[7]);                   \
    u32 y4 = cvtpk(S1[8], S1[9]), y5 = cvtpk(S1[10], S1[11]);                 \
    u32 y6 = cvtpk(S1[12], S1[13]), y7 = cvtpk(S1[14], S1[15]);               \
    plswap(y0, y2);                                                           \
    plswap(y1, y3);                                                           \
    plswap(y4, y6);                                                           \
    plswap(y5, y7);                                                           \
    pa2[0] = y0; pa2[1] = y1; pa2[2] = y2; pa2[3] = y3;                       \
    pa3[0] = y4; pa3[1] = y5; pa3[2] = y6; pa3[3] = y7;                       \
  }

// PV over one 64-j half; JB = V chunk base (0 for j 0..63, 8 for 64..127)
#define PVH(VCUR, JB)                                                         \
  asm volatile("s_nop 2");                                                    \
  __builtin_amdgcn_s_setprio(1);                                              \
  {                                                                           \
    u32x4 vf0, vf1;                                                           \
    _Pragma("unroll") for (int kbk = 0; kbk < 4; ++kbk) {                     \
      const int jc = (JB) + (kbk << 1) + h;                                   \
      const int co = (jc ^ (lq & 15)) << 4;                                   \
      vf0 = *(const u32x4*)((VCUR) + lq * 256 + co);                          \
      vf1 = *(const u32x4*)((VCUR) + (32 + lq) * 256 + co);                   \
      if (kbk == 0) { mfma32(oacc0, pa0, vf0); mfma32(oacc1, pa0, vf1); }     \
      if (kbk == 1) { mfma32(oacc0, pa1, vf0); mfma32(oacc1, pa1, vf1); }     \
      if (kbk == 2) { mfma32(oacc0, pa2, vf0); mfma32(oacc1, pa2, vf1); }     \
      if (kbk == 3) { mfma32(oacc0, pa3, vf0); mfma32(oacc1, pa3, vf1); }     \
    }                                                                         \
  }                                                                           \
  __builtin_amdgcn_s_setprio(0);

  issue(0, 0);
  for (int kt = 0; kt < 16; ++kt) {
    const int cur = kt & 1;
    if (kt < 15) {
      issue(kt + 1, cur ^ 1);
      asm volatile("s_waitcnt vmcnt(4)" ::: "memory");  // own kt loads landed
    } else {
      asm volatile("s_waitcnt vmcnt(0)" ::: "memory");
    }
    BAR();
    const char* Kc = Ks[cur];
    const char* Vc = Vs[cur];
    // S^T: 4 j-blocks of 32 rows, cols q
    f32x16 s0 = (f32x16)0.0f, s1 = (f32x16)0.0f;
    f32x16 s2 = (f32x16)0.0f, s3 = (f32x16)0.0f;
    __builtin_amdgcn_s_setprio(1);
#pragma unroll
    for (int dk = 0; dk < 4; ++dk) {
      const int co = ((((dk << 1) + h) ^ (lq & 7)) << 4);
      u32x4 kf0 = *(const u32x4*)(Kc + lq * 128 + co);
      u32x4 kf1 = *(const u32x4*)(Kc + (32 + lq) * 128 + co);
      u32x4 kf2 = *(const u32x4*)(Kc + (64 + lq) * 128 + co);
      u32x4 kf3 = *(const u32x4*)(Kc + (96 + lq) * 128 + co);
      mfma32(s0, kf0, qf[dk]);
      mfma32(s1, kf1, qf[dk]);
      mfma32(s2, kf2, qf[dk]);
      mfma32(s3, kf3, qf[dk]);
    }
    __builtin_amdgcn_s_setprio(0);
    HZ();
    EXPTREE(s0)
    EXPTREE(s1)
    {
      u32x4 pa0, pa1, pa2, pa3;
      PACK(s0, s1)
      PVH(Vc, 0)
    }
    EXPTREE(s2)
    EXPTREE(s3)
    {
      u32x4 pa0, pa1, pa2, pa3;
      PACK(s2, s3)
      PVH(Vc, 8)
    }
    BAR();
  }
#undef PVH
#undef PACK
#undef EXPTREE
  HZ();
  // epilogue: combine lane-half l, normalize, fp16 store
  const float invl = 1.0f / (lrow + __shfl_xor(lrow, 32));
#pragma unroll
  for (int r = 0; r < 16; ++r) {
    const int qr = (r & 3) + 8 * (r >> 2) + 4 * h;
    const float fr = __shfl(invl, qr);
    const size_t srow = (size_t)(b * 2048 + (qt << 8) + (w << 5) + qr);
    const size_t base = srow * 1024 + (hh << 6) + lq;
    o16[base] = f2h(oacc0[r] * fr);
    o16[base + 32] = f2h(oacc1[r] * fr);
  }
}

extern "C" void kernel_launch(void* const* d_in, const int* in_sizes, int n_in,
                              void* d_out, int out_size, void* d_ws,
                              size_t ws_size, hipStream_t stream) {
  const float* x = (const float*)d_in[0];
  const float* w1 = (const float*)d_in[1];
  const float* w2 = (const float*)d_in[2];
  char* ws = (char*)d_ws;
  float2* tab = (float2*)(ws + TAB_B);
  u16* qbf = (u16*)(ws + QBF_B);
  u16* kbf = (u16*)(ws + KBF_B);
  u16* vtbf = (u16*)(ws + VTB_B);
  u16* w2h = (u16*)(ws + W2H_B);
  u16* xbf = (u16*)(ws + XBF_B);
  u16* w1bf = (u16*)(ws + W1BF_B);
  u16* o16 = (u16*)(ws + O16_B);
  float* out = (float*)d_out;

  prep_kernel<<<dim3(2304), dim3(256), 0, stream>>>(x, w1, w2, tab, xbf, w1bf,
                                                    w2h);
  gemm_bt<0, 4><<<dim3(32 * 24), dim3(256), 0, stream>>>(
      xbf, w1bf, 24, 16, 96, tab, qbf, kbf, vtbf, nullptr);
  attn_mfma<<<dim3(256), dim3(512), 0, stream>>>(qbf, kbf, vtbf, o16);
  gemm_bt<1, 2><<<dim3(32 * 16), dim3(256), 0, stream>>>(
      o16, w2h, 16, 16, 64, nullptr, nullptr, nullptr, nullptr, out);
}

// Round 20
// 105.238 us; speedup vs baseline: 1.0065x; 1.0033x over previous
//
#include <hip/hip_runtime.h>
#include <math.h>

typedef unsigned short u16;
typedef unsigned int u32;
typedef float f32x4 __attribute__((ext_vector_type(4)));
typedef float f32x16 __attribute__((ext_vector_type(16)));
typedef u32 u32x4 __attribute__((ext_vector_type(4)));

// ---- problem dims: B=2 S=2048 E=1024 H=16 HD=64 ----
static const size_t TAB_B  = 0;         // float2[2048][32]
static const size_t QBF_B  = 524288;    // bf16 [2][16][2048][64], pre-scaled 0.125*log2e
static const size_t KBF_B  = 8912896;   // bf16 [2][16][2048][64]
static const size_t VTB_B  = 17301504;  // bf16 [2][16][64][2048]  (V transposed)
static const size_t W2H_B  = 25690112;  // fp16 [1024][1024]
static const size_t XBF_B  = 29884416;  // bf16 x      (dead after QKV gemm)
static const size_t W1BF_B = 38273024;  // bf16 w1     (dead after QKV gemm)
static const size_t O16_B  = 29884416;  // fp16 [4096][1024], reuses XBF

#if __has_builtin(__builtin_amdgcn_exp2f)
#define EXP2(x) __builtin_amdgcn_exp2f(x)
#else
#define EXP2(x) __expf(0.69314718056f * (x))
#endif

__device__ __forceinline__ u16 f2bf(float f) {
  u32 u = __builtin_bit_cast(u32, f);
  u += 0x7fffu + ((u >> 16) & 1u);
  return (u16)(u >> 16);
}
__device__ __forceinline__ float bf2f(u16 h) {
  return __builtin_bit_cast(float, (u32)h << 16);
}
__device__ __forceinline__ u16 f2h(float f) {
  _Float16 h = (_Float16)f;
  return __builtin_bit_cast(u16, h);
}
// packed f32x2 -> bf16x2 (T12; single instruction, RNE)
__device__ __forceinline__ u32 cvtpk(float a, float b) {
  u32 r;
  asm("v_cvt_pk_bf16_f32 %0, %1, %2" : "=v"(r) : "v"(a), "v"(b));
  return r;  // a low16, b high16
}
// v_permlane32_swap_b32 a, b: a' = {lo: a_lo, hi: b_lo}; b' = {lo: a_hi, hi: b_hi}
__device__ __forceinline__ void plswap(u32& a, u32& b) {
  asm volatile("v_permlane32_swap_b32 %0, %1" : "+v"(a), "+v"(b));
}
__device__ __forceinline__ void mfma16(f32x4& d, u32x4 a, u32x4 b) {
  asm volatile("v_mfma_f32_16x16x32_bf16 %0, %1, %2, %0"
               : "+v"(d)
               : "v"(a), "v"(b));
}
__device__ __forceinline__ void mfma16f(f32x4& d, u32x4 a, u32x4 b) {
  asm volatile("v_mfma_f32_16x16x32_f16 %0, %1, %2, %0"
               : "+v"(d)
               : "v"(a), "v"(b));
}
__device__ __forceinline__ void mfma32(f32x16& d, u32x4 a, u32x4 b) {
  asm volatile("v_mfma_f32_32x32x16_bf16 %0, %1, %2, %0"
               : "+v"(d)
               : "v"(a), "v"(b));
}
// async global->LDS, 16B per lane; lds dest = wave-uniform base (+lane*16 by HW)
__device__ __forceinline__ void gld16(const void* g, void* l) {
  __builtin_amdgcn_global_load_lds(
      (const __attribute__((address_space(1))) void*)(void*)g,
      (__attribute__((address_space(3))) void*)l, 16, 0, 0);
}
// MFMA->VALU read hazard fence + scheduling pin (rule #18)
#define HZ()                                            \
  do {                                                  \
    asm volatile("s_nop 7\ns_nop 7\ns_nop 7\ns_nop 7"); \
    __builtin_amdgcn_sched_barrier(0);                  \
  } while (0)
// RAW workgroup barrier (no implicit vmcnt(0) drain; HK protocol, r15-proven)
#define BAR()                          \
  do {                                 \
    __builtin_amdgcn_s_barrier();      \
    __builtin_amdgcn_sched_barrier(0); \
  } while (0)

// ============================================================================
// prep: rope table + bf16/fp16 converts, fused (one launch).
// ============================================================================
__global__ __launch_bounds__(256) void prep_kernel(
    const float* __restrict__ x, const float* __restrict__ w1,
    const float* __restrict__ w2, float2* __restrict__ tab,
    u16* __restrict__ xbf, u16* __restrict__ w1bf, u16* __restrict__ w2h) {
  const int blk = blockIdx.x;
  const int t = threadIdx.x;
  if (blk < 256) {
    const int idx = (blk << 8) + t;
    const int s = idx >> 5, i = idx & 31;
    double theta = pow(10000.0, -((double)(2 * i)) / 64.0);
    float ang = (float)s * (float)theta;
    tab[idx] = make_float2(cosf(ang), sinf(ang));
  } else if (blk < 1280) {
    int i = ((blk - 256) << 8) + t;
#pragma unroll
    for (int r = 0; r < 4; ++r, i += 262144) {
      float4 v = ((const float4*)x)[i];
      ushort4 o;
      o.x = f2bf(v.x); o.y = f2bf(v.y); o.z = f2bf(v.z); o.w = f2bf(v.w);
      ((ushort4*)xbf)[i] = o;
    }
  } else if (blk < 2048) {
    int i = ((blk - 1280) << 8) + t;
#pragma unroll
    for (int r = 0; r < 4; ++r, i += 196608) {
      float4 v = ((const float4*)w1)[i];
      ushort4 o;
      o.x = f2bf(v.x); o.y = f2bf(v.y); o.z = f2bf(v.z); o.w = f2bf(v.w);
      ((ushort4*)w1bf)[i] = o;
    }
  } else {
    int i = ((blk - 2048) << 8) + t;
#pragma unroll
    for (int r = 0; r < 4; ++r, i += 65536) {
      float4 v = ((const float4*)w2)[i];
      ushort4 o;
      o.x = f2h(v.x); o.y = f2h(v.y); o.z = f2h(v.z); o.w = f2h(v.w);
      ((ushort4*)w2h)[i] = o;
    }
  }
}

// ============================================================================
// B^T GEMM (QKV): 128x128 tile, BK=64, 4 waves (2x2), gld_lds staging, T1
// XCD-swizzled grid. q/k -> RoPE scatter; V -> LDS-transposed coalesced V^T.
// ============================================================================
template <int MODE, int NI>
__global__ __launch_bounds__(256) void gemm_bt(
    const u16* __restrict__ Ahi, const u16* __restrict__ Bhi, int nbn, int nkb,
    int cpx, const float2* __restrict__ tab, u16* __restrict__ qd,
    u16* __restrict__ kd, u16* __restrict__ vtd, float* __restrict__ fout) {
  __shared__ __align__(16) char SMEM[MODE == 0 ? 34816 : 16384 + NI * 4096];
  char* As = SMEM;
  char* Bs = SMEM + 16384;
  const int bid = blockIdx.x;
  const int wgid = (bid & 7) * cpx + (bid >> 3);  // T1 XCD remap (nwg%8==0)
  const int bm = wgid / nbn;
  const int bn = wgid % nbn;
  const int m0 = bm << 7;
  const int n0 = bn * (NI << 5);
  const int t = threadIdx.x;
  const int w = t >> 6;
  const int lane = t & 63;
  const int lr = lane & 15;
  const int lg = lane >> 4;
  const int wr0 = (w >> 1) << 6;
  const int wc0 = (w & 1) * (NI << 4);
  const int srow0 = t >> 3;
  const int sblk = t & 7;

  f32x4 acc[4][NI];
#pragma unroll
  for (int mi = 0; mi < 4; ++mi)
#pragma unroll
    for (int ni = 0; ni < NI; ++ni) acc[mi][ni] = (f32x4)0.0f;

  for (int kb = 0; kb < nkb; ++kb) {
    const int k0 = kb << 6;
    if (kb) __syncthreads();
#pragma unroll
    for (int r = 0; r < 4; ++r) {
      const int row = srow0 + (r << 5);
      const int g = sblk ^ (row & 7);
      gld16(Ahi + (size_t)(m0 + row) * 1024 + k0 + (g << 3),
            As + (r << 12) + (w << 10));
    }
#pragma unroll
    for (int r = 0; r < NI; ++r) {
      const int row = srow0 + (r << 5);
      const int g = sblk ^ (row & 7);
      gld16(Bhi + (size_t)(n0 + row) * 1024 + k0 + (g << 3),
            Bs + (r << 12) + (w << 10));
    }
    asm volatile("s_waitcnt vmcnt(0)" ::: "memory");
    __syncthreads();
#pragma unroll
    for (int kk = 0; kk < 2; ++kk) {
      u32x4 af[4], bf[NI];
#pragma unroll
      for (int mi = 0; mi < 4; ++mi) {
        const int row = wr0 + (mi << 4) + lr;
        af[mi] = *(const u32x4*)(As + row * 128 +
                                 ((((kk << 2) + lg) ^ (row & 7)) << 4));
      }
#pragma unroll
      for (int ni = 0; ni < NI; ++ni) {
        const int row = wc0 + (ni << 4) + lr;
        bf[ni] = *(const u32x4*)(Bs + row * 128 +
                                 ((((kk << 2) + lg) ^ (row & 7)) << 4));
      }
      asm volatile("s_nop 1");
      __builtin_amdgcn_s_setprio(1);
#pragma unroll
      for (int mi = 0; mi < 4; ++mi)
#pragma unroll
        for (int ni = 0; ni < NI; ++ni) {
          if constexpr (MODE == 1)
            mfma16f(acc[mi][ni], af[mi], bf[ni]);
          else
            mfma16(acc[mi][ni], af[mi], bf[ni]);
        }
      __builtin_amdgcn_s_setprio(0);
    }
  }
  HZ();
  if constexpr (MODE == 0) {
    if (n0 >= 2048) {
      // ---- V path: LDS transpose -> coalesced V^T stores ----
      u16* Vt = (u16*)SMEM;
      __syncthreads();  // all waves done reading As/Bs before overlay write
#pragma unroll
      for (int mi = 0; mi < 4; ++mi)
#pragma unroll
        for (int ni = 0; ni < NI; ++ni)
#pragma unroll
          for (int i = 0; i < 4; ++i) {
            const int dl = wc0 + (ni << 4) + lr;
            const int sl = wr0 + (mi << 4) + (lg << 2) + i;
            Vt[dl * 136 + sl] = f2bf(acc[mi][ni][i]);
          }
      __syncthreads();
      const int row = t >> 1;
      const int half = t & 1;
      const int hh2 = (n0 - 2048 + row) >> 6;
      const int d2 = (n0 - 2048 + row) & 63;
      const int b2 = m0 >> 11;
      u16* dst = vtd + (((size_t)(b2 * 16 + hh2) * 64 + d2) * 2048) +
                 (m0 & 2047) + half * 64;
      const u16* src = Vt + row * 136 + half * 64;
#pragma unroll
      for (int c = 0; c < 8; ++c)
        *(u32x4*)(dst + (c << 3)) = *(const u32x4*)(src + (c << 3));
      return;
    }
  }
#pragma unroll
  for (int mi = 0; mi < 4; ++mi)
#pragma unroll
    for (int ni = 0; ni < NI; ++ni)
#pragma unroll
      for (int i = 0; i < 4; ++i) {
        float val = acc[mi][ni][i];
        const int grow = m0 + wr0 + (mi << 4) + (lg << 2) + i;
        const int col = n0 + wc0 + (ni << 4) + lr;
        if (MODE == 0) {
          const int b = grow >> 11, s = grow & 2047;
          const int which = col >> 10, hh = (col >> 6) & 15, d = col & 63;
          const size_t base = (size_t)((b << 4) + hh);
          float other = __shfl_xor(val, 1);
          float2 cs = tab[(s << 5) + (d >> 1)];
          float r = (d & 1) ? fmaf(val, cs.x, other * cs.y)
                            : fmaf(val, cs.x, -other * cs.y);
          // fold (1/sqrt(HD)) * log2(e) into q -> softmax in exp2 domain
          if (which == 0) r *= 0.18033688011f;
          u16* dstp = which ? kd : qd;
          dstp[(base * 2048 + s) * 64 + d] = f2bf(r);
        } else {
          fout[(size_t)grow * 1024 + col] = val;
        }
      }
}

// ============================================================================
// Final GEMM, DOUBLE-BUFFERED (attn-proven counted-vmcnt + raw-barrier
// protocol): out[m][n] = sum_k o16[m][k]*w2h[n][k], fp16 MFMA, 128x64 tile,
// BK=64, 4 waves. Per K-step: issue next tile's 6 gld16 (steady 12 in
// flight), vmcnt(6), BAR, compute, BAR. LDS 49KB -> 2 blocks/CU at grid 512.
// ============================================================================
__global__ __launch_bounds__(256) void gemm_out_db(
    const u16* __restrict__ Ah, const u16* __restrict__ Bh, int nbn, int nkb,
    int cpx, float* __restrict__ fout) {
  __shared__ __align__(16) char As[2][16384];
  __shared__ __align__(16) char Bs[2][8192];
  const int bid = blockIdx.x;
  const int wgid = (bid & 7) * cpx + (bid >> 3);  // T1 XCD remap
  const int bm = wgid / nbn;
  const int bn = wgid % nbn;
  const int m0 = bm << 7;
  const int n0 = bn << 6;
  const int t = threadIdx.x;
  const int w = t >> 6;
  const int lane = t & 63;
  const int lr = lane & 15;
  const int lg = lane >> 4;
  const int wr0 = (w >> 1) << 6;
  const int wc0 = (w & 1) << 5;
  const int srow0 = t >> 3;
  const int sblk = t & 7;

  auto issue = [&](int kb_, int buf_) {
    const int k0 = kb_ << 6;
#pragma unroll
    for (int r = 0; r < 4; ++r) {
      const int row = srow0 + (r << 5);
      const int g = sblk ^ (row & 7);
      gld16(Ah + (size_t)(m0 + row) * 1024 + k0 + (g << 3),
            As[buf_] + (r << 12) + (w << 10));
    }
#pragma unroll
    for (int r = 0; r < 2; ++r) {
      const int row = srow0 + (r << 5);
      const int g = sblk ^ (row & 7);
      gld16(Bh + (size_t)(n0 + row) * 1024 + k0 + (g << 3),
            Bs[buf_] + (r << 12) + (w << 10));
    }
  };

  f32x4 acc[4][2];
#pragma unroll
  for (int mi = 0; mi < 4; ++mi)
#pragma unroll
    for (int ni = 0; ni < 2; ++ni) acc[mi][ni] = (f32x4)0.0f;

  issue(0, 0);
  for (int kb = 0; kb < nkb; ++kb) {
    const int cur = kb & 1;
    if (kb < nkb - 1) {
      issue(kb + 1, cur ^ 1);
      asm volatile("s_waitcnt vmcnt(6)" ::: "memory");  // own kb loads landed
    } else {
      asm volatile("s_waitcnt vmcnt(0)" ::: "memory");
    }
    BAR();
    const char* Ac = As[cur];
    const char* Bc = Bs[cur];
#pragma unroll
    for (int kk = 0; kk < 2; ++kk) {
      u32x4 af[4], bf[2];
#pragma unroll
      for (int mi = 0; mi < 4; ++mi) {
        const int row = wr0 + (mi << 4) + lr;
        af[mi] = *(const u32x4*)(Ac + row * 128 +
                                 ((((kk << 2) + lg) ^ (row & 7)) << 4));
      }
#pragma unroll
      for (int ni = 0; ni < 2; ++ni) {
        const int row = wc0 + (ni << 4) + lr;
        bf[ni] = *(const u32x4*)(Bc + row * 128 +
                                 ((((kk << 2) + lg) ^ (row & 7)) << 4));
      }
      asm volatile("s_nop 1");
      __builtin_amdgcn_s_setprio(1);
#pragma unroll
      for (int mi = 0; mi < 4; ++mi)
#pragma unroll
        for (int ni = 0; ni < 2; ++ni) mfma16f(acc[mi][ni], af[mi], bf[ni]);
      __builtin_amdgcn_s_setprio(0);
    }
    BAR();  // buffer write-protect for next iteration's issue
  }
  HZ();
#pragma unroll
  for (int mi = 0; mi < 4; ++mi)
#pragma unroll
    for (int ni = 0; ni < 2; ++ni)
#pragma unroll
      for (int i = 0; i < 4; ++i) {
        const int grow = m0 + wr0 + (mi << 4) + (lg << 2) + i;
        const int col = n0 + wc0 + (ni << 4) + lr;
        fout[(size_t)grow * 1024 + col] = acc[mi][ni][i];
      }
}

// ============================================================================
// Flash attention (r19 frozen): 8 waves x 32 q rows (q-tile 256), KVBLK=128
// dbuf, counted vmcnt(4), raw BARs, fixed-max exp2 softmax, T12 in-reg P.
// Plateau analysis (r14-r19): MFMA 27% / VALU 38% (exp2-intrinsic) / LDS pipe
// ~42% (8x cross-wave K/V read redundancy); structure at its floor.
// ============================================================================
__global__ __launch_bounds__(512) void attn_mfma(
    const u16* __restrict__ q, const u16* __restrict__ k,
    const u16* __restrict__ vt, u16* __restrict__ o16) {
  __shared__ __align__(16) char Ks[2][16384];  // [128 j][64 d], XOR (row&7)
  __shared__ __align__(16) char Vs[2][16384];  // [64 dd][128 j], XOR (row&15)
  const int bid = blockIdx.x;
  const int swz = (bid & 7) * 32 + (bid >> 3);  // XCD remap (256%8==0)
  const int qt = swz & 7;                        // 8 q-tiles of 256 rows
  const int hh = (swz >> 3) & 15;
  const int b = swz >> 7;
  const int t = threadIdx.x;  // 0..511
  const int w = t >> 6;       // 8 waves
  const int lane = t & 63;
  const int lq = lane & 31;  // q col / j row / dd row within 32
  const int h = lane >> 5;   // lane half

  const size_t bh = (size_t)((b << 4) + hh);
  const u16* qb = q + (bh * 2048 + (size_t)(qt * 256 + w * 32)) * 64;
  const u16* kb = k + bh * 2048 * 64;
  const u16* vb = vt + bh * 64 * 2048;

  // Q B-frags: col q=lq, d slots = dk*16 + 8*h + 0..7
  u32x4 qf[4];
#pragma unroll
  for (int dk = 0; dk < 4; ++dk)
    qf[dk] = *(const u32x4*)(qb + lq * 64 + dk * 16 + h * 8);

  // stage one 128-j tile: K 16KB (128r x 8c) + V 16KB (64r x 16c); 512 thr x
  // 2 rounds x {K,V} = 4 gld16/thread
  auto issue = [&](int kt_, int buf_) {
    const u16* ksrc = kb + (size_t)kt_ * 8192;
#pragma unroll
    for (int r = 0; r < 2; ++r) {
      const int ci = (r << 9) + (w << 6) + lane;
      const int dstb = ((r << 9) + (w << 6)) << 4;  // wave-uniform
      {
        const int row = ci >> 3, ch = ci & 7;
        const int g = ch ^ (row & 7);
        gld16(ksrc + row * 64 + (g << 3), &Ks[buf_][dstb]);
      }
      {
        const int row = ci >> 4, ch = ci & 15;
        const int g = ch ^ (row & 15);
        gld16(vb + (size_t)row * 2048 + kt_ * 128 + (g << 3), &Vs[buf_][dstb]);
      }
    }
  };

  f32x16 oacc0 = (f32x16)0.0f, oacc1 = (f32x16)0.0f;
  float lrow = 0.0f;  // lane-half partial row sum; combined in epilogue

// exp2 all 16 then 8-way-ILP tree sum into lrow
#define EXPTREE(S)                                                            \
  {                                                                           \
    _Pragma("unroll") for (int i = 0; i < 16; ++i) S[i] = EXP2(S[i]);         \
    float a0 = (S[0] + S[1]) + (S[2] + S[3]);                                 \
    float a1 = (S[4] + S[5]) + (S[6] + S[7]);                                 \
    float a2 = (S[8] + S[9]) + (S[10] + S[11]);                               \
    float a3 = (S[12] + S[13]) + (S[14] + S[15]);                             \
    lrow += (a0 + a1) + (a2 + a3);                                            \
  }

// T12 pack of one 64-j half (S0 = j-block lo32, S1 = hi32) into pa0..pa3
#define PACK(S0, S1)                                                          \
  {                                                                           \
    u32 w0 = cvtpk(S0[0], S0[1]), w1 = cvtpk(S0[2], S0[3]);                   \
    u32 w2 = cvtpk(S0[4], S0[5]), w3 = cvtpk(S0[6], S0[7]);                   \
    u32 w4 = cvtpk(S0[8], S0[9]), w5 = cvtpk(S0[10], S0[11]);                 \
    u32 w6 = cvtpk(S0[12], S0[13]), w7 = cvtpk(S0[14], S0[15]);               \
    plswap(w0, w2);                                                           \
    plswap(w1, w3);                                                           \
    plswap(w4, w6);                                                           \
    plswap(w5, w7);                                                           \
    pa0[0] = w0; pa0[1] = w1; pa0[2] = w2; pa0[3] = w3;                       \
    pa1[0] = w4; pa1[1] = w5; pa1[2] = w6; pa1[3] = w7;                       \
    u32 y0 = cvtpk(S1[0], S1[1]), y1 = cvtpk(S1[2], S1[3]);                   \
    u32 y2 = cvtpk(S1[4], S1[5]), y3 = cvtpk(S1[6], S1[7]);                   \
    u32 y4 = cvtpk(S1[8], S1[9]), y5 = cvtpk(S1[10], S1[11]);                 \
    u32 y6 = cvtpk(S1[12], S1[13]), y7 = cvtpk(S1[14], S1[15]);               \
    plswap(y0, y2);                                                           \
    plswap(y1, y3);                                                           \
    plswap(y4, y6);                                                           \
    plswap(y5, y7);                                                           \
    pa2[0] = y0; pa2[1] = y1; pa2[2] = y2; pa2[3] = y3;                       \
    pa3[0] = y4; pa3[1] = y5; pa3[2] = y6; pa3[3] = y7;                       \
  }

// PV over one 64-j half; JB = V chunk base (0 for j 0..63, 8 for 64..127)
#define PVH(VCUR, JB)                                                         \
  asm volatile("s_nop 2");                                                    \
  __builtin_amdgcn_s_setprio(1);                                              \
  {                                                                           \
    u32x4 vf0, vf1;                                                           \
    _Pragma("unroll") for (int kbk = 0; kbk < 4; ++kbk) {                     \
      const int jc = (JB) + (kbk << 1) + h;                                   \
      const int co = (jc ^ (lq & 15)) << 4;                                   \
      vf0 = *(const u32x4*)((VCUR) + lq * 256 + co);                          \
      vf1 = *(const u32x4*)((VCUR) + (32 + lq) * 256 + co);                   \
      if (kbk == 0) { mfma32(oacc0, pa0, vf0); mfma32(oacc1, pa0, vf1); }     \
      if (kbk == 1) { mfma32(oacc0, pa1, vf0); mfma32(oacc1, pa1, vf1); }     \
      if (kbk == 2) { mfma32(oacc0, pa2, vf0); mfma32(oacc1, pa2, vf1); }     \
      if (kbk == 3) { mfma32(oacc0, pa3, vf0); mfma32(oacc1, pa3, vf1); }     \
    }                                                                         \
  }                                                                           \
  __builtin_amdgcn_s_setprio(0);

  issue(0, 0);
  for (int kt = 0; kt < 16; ++kt) {
    const int cur = kt & 1;
    if (kt < 15) {
      issue(kt + 1, cur ^ 1);
      asm volatile("s_waitcnt vmcnt(4)" ::: "memory");  // own kt loads landed
    } else {
      asm volatile("s_waitcnt vmcnt(0)" ::: "memory");
    }
    BAR();
    const char* Kc = Ks[cur];
    const char* Vc = Vs[cur];
    // S^T: 4 j-blocks of 32 rows, cols q
    f32x16 s0 = (f32x16)0.0f, s1 = (f32x16)0.0f;
    f32x16 s2 = (f32x16)0.0f, s3 = (f32x16)0.0f;
    __builtin_amdgcn_s_setprio(1);
#pragma unroll
    for (int dk = 0; dk < 4; ++dk) {
      const int co = ((((dk << 1) + h) ^ (lq & 7)) << 4);
      u32x4 kf0 = *(const u32x4*)(Kc + lq * 128 + co);
      u32x4 kf1 = *(const u32x4*)(Kc + (32 + lq) * 128 + co);
      u32x4 kf2 = *(const u32x4*)(Kc + (64 + lq) * 128 + co);
      u32x4 kf3 = *(const u32x4*)(Kc + (96 + lq) * 128 + co);
      mfma32(s0, kf0, qf[dk]);
      mfma32(s1, kf1, qf[dk]);
      mfma32(s2, kf2, qf[dk]);
      mfma32(s3, kf3, qf[dk]);
    }
    __builtin_amdgcn_s_setprio(0);
    HZ();
    EXPTREE(s0)
    EXPTREE(s1)
    {
      u32x4 pa0, pa1, pa2, pa3;
      PACK(s0, s1)
      PVH(Vc, 0)
    }
    EXPTREE(s2)
    EXPTREE(s3)
    {
      u32x4 pa0, pa1, pa2, pa3;
      PACK(s2, s3)
      PVH(Vc, 8)
    }
    BAR();
  }
#undef PVH
#undef PACK
#undef EXPTREE
  HZ();
  // epilogue: combine lane-half l, normalize, fp16 store
  const float invl = 1.0f / (lrow + __shfl_xor(lrow, 32));
#pragma unroll
  for (int r = 0; r < 16; ++r) {
    const int qr = (r & 3) + 8 * (r >> 2) + 4 * h;
    const float fr = __shfl(invl, qr);
    const size_t srow = (size_t)(b * 2048 + (qt << 8) + (w << 5) + qr);
    const size_t base = srow * 1024 + (hh << 6) + lq;
    o16[base] = f2h(oacc0[r] * fr);
    o16[base + 32] = f2h(oacc1[r] * fr);
  }
}

extern "C" void kernel_launch(void* const* d_in, const int* in_sizes, int n_in,
                              void* d_out, int out_size, void* d_ws,
                              size_t ws_size, hipStream_t stream) {
  const float* x = (const float*)d_in[0];
  const float* w1 = (const float*)d_in[1];
  const float* w2 = (const float*)d_in[2];
  char* ws = (char*)d_ws;
  float2* tab = (float2*)(ws + TAB_B);
  u16* qbf = (u16*)(ws + QBF_B);
  u16* kbf = (u16*)(ws + KBF_B);
  u16* vtbf = (u16*)(ws + VTB_B);
  u16* w2h = (u16*)(ws + W2H_B);
  u16* xbf = (u16*)(ws + XBF_B);
  u16* w1bf = (u16*)(ws + W1BF_B);
  u16* o16 = (u16*)(ws + O16_B);
  float* out = (float*)d_out;

  prep_kernel<<<dim3(2304), dim3(256), 0, stream>>>(x, w1, w2, tab, xbf, w1bf,
                                                    w2h);
  gemm_bt<0, 4><<<dim3(32 * 24), dim3(256), 0, stream>>>(
      xbf, w1bf, 24, 16, 96, tab, qbf, kbf, vtbf, nullptr);
  attn_mfma<<<dim3(256), dim3(512), 0, stream>>>(qbf, kbf, vtbf, o16);
  gemm_out_db<<<dim3(32 * 16), dim3(256), 0, stream>>>(o16, w2h, 16, 16, 64,
                                                       out);
}